// Round 2
// baseline (663.344 us; speedup 1.0000x reference)
//
#include <hip/hip_runtime.h>
#include <hip/hip_bf16.h>

#define DIMI 64
#define DIMO 40

// ---------------- utility kernels ----------------

__global__ void k_zero(int* __restrict__ p, int n) {
    int i = blockIdx.x * blockDim.x + threadIdx.x;
    if (i < n) p[i] = 0;
}

__global__ void k_hist(const int* __restrict__ dst, int* __restrict__ counts, int E) {
    int i = blockIdx.x * blockDim.x + threadIdx.x;
    if (i < E) atomicAdd(&counts[dst[i]], 1);
}

__global__ void k_dinv(const int* __restrict__ counts, float* __restrict__ dinv, int N) {
    int i = blockIdx.x * blockDim.x + threadIdx.x;
    if (i < N) dinv[i] = rsqrtf((float)(counts[i] + 1));  // +1 = self loop
}

// per-block sums of counts -> partial[block]
__global__ void k_block_sums(const int* __restrict__ counts, int* __restrict__ partial, int n) {
    __shared__ int s[256];
    int i = blockIdx.x * 256 + threadIdx.x;
    s[threadIdx.x] = (i < n) ? counts[i] : 0;
    __syncthreads();
    for (int st = 128; st > 0; st >>= 1) {
        if (threadIdx.x < st) s[threadIdx.x] += s[threadIdx.x + st];
        __syncthreads();
    }
    if (threadIdx.x == 0) partial[blockIdx.x] = s[0];
}

// single block, 1024 threads: exclusive scan of partial[0..nb)
__global__ void k_scan_partials(int* partial, int nb) {
    __shared__ int s[1024];
    int t = threadIdx.x;
    int orig = (t < nb) ? partial[t] : 0;
    s[t] = orig;
    __syncthreads();
    for (int o = 1; o < 1024; o <<= 1) {
        int v = (t >= o) ? s[t - o] : 0;
        __syncthreads();
        s[t] += v;
        __syncthreads();
    }
    if (t < nb) partial[t] = s[t] - orig;  // exclusive
}

// block-local exclusive scan + partial offset -> off[i]
__global__ void k_scan_final(const int* __restrict__ counts, const int* __restrict__ partial,
                             int* __restrict__ off, int n) {
    __shared__ int s[256];
    int t = threadIdx.x;
    int i = blockIdx.x * 256 + t;
    int orig = (i < n) ? counts[i] : 0;
    s[t] = orig;
    __syncthreads();
    for (int o = 1; o < 256; o <<= 1) {
        int v = (t >= o) ? s[t - o] : 0;
        __syncthreads();
        s[t] += v;
        __syncthreads();
    }
    if (i < n) off[i] = s[t] - orig + partial[blockIdx.x];
}

__global__ void k_scatter(const int* __restrict__ src, const int* __restrict__ dst,
                          const int* __restrict__ off, int* __restrict__ cursor,
                          int* __restrict__ col, int E) {
    int i = blockIdx.x * blockDim.x + threadIdx.x;
    if (i < E) {
        int d = dst[i];
        int p = off[d] + atomicAdd(&cursor[d], 1);
        col[p] = src[i];
    }
}

// Wc = W_sgc @ W_head (64x40); bc = b_sgc @ W_head + b_head (40)
__global__ void k_wc(const float* __restrict__ Wsgc, const float* __restrict__ bsgc,
                     const float* __restrict__ Whead, const float* __restrict__ bhead,
                     float* __restrict__ Wc, float* __restrict__ bc) {
    __shared__ float sA[DIMI * DIMI];
    __shared__ float sB[DIMI * DIMO];
    int t = threadIdx.x;
    for (int i = t; i < DIMI * DIMI; i += 256) sA[i] = Wsgc[i];
    for (int i = t; i < DIMI * DIMO; i += 256) sB[i] = Whead[i];
    __syncthreads();
    for (int o = t; o < DIMI * DIMO; o += 256) {
        int k = o / DIMO, j = o % DIMO;
        float acc = 0.f;
        #pragma unroll
        for (int m = 0; m < DIMI; m++) acc += sA[k * DIMI + m] * sB[m * DIMO + j];
        Wc[o] = acc;
    }
    if (t < DIMO) {
        float acc = bhead[t];
        #pragma unroll
        for (int m = 0; m < DIMI; m++) acc += bsgc[m] * sB[m * DIMO + t];
        bc[t] = acc;
    }
}

// y[N,40] = dinv[n] * (x[N,64] @ Wc[64,40])   (u0 = D^{-1/2} x Wc)
__global__ void k_proj(const float* __restrict__ x, const float* __restrict__ Wc,
                       const float* __restrict__ dinv, float* __restrict__ y, int N) {
    __shared__ float sX[32 * DIMI];
    __shared__ float sW[DIMI * DIMO];
    int t = threadIdx.x;
    int n0 = blockIdx.x * 32;
    for (int i = t; i < DIMI * DIMO; i += 256) sW[i] = Wc[i];
    for (int i = t; i < 32 * DIMI; i += 256) {
        int r = n0 + i / DIMI;
        sX[i] = (r < N) ? x[(long)r * DIMI + (i & (DIMI - 1))] : 0.f;
    }
    __syncthreads();
    for (int o = t; o < 32 * DIMO; o += 256) {
        int li = o / DIMO, j = o % DIMO;
        int node = n0 + li;
        if (node < N) {
            float acc = 0.f;
            #pragma unroll
            for (int k = 0; k < DIMI; k++) acc += sX[li * DIMI + k] * sW[k * DIMO + j];
            y[(long)node * DIMO + j] = dinv[node] * acc;
        }
    }
}

// one 64-lane wave per node; lane = feature (lanes 40..63 duplicate lane 39).
// u-space hop: out = scale * ( sum_{nbr} in[nbr] + in[self] )
// scale = dinv^2 for intermediate hops, dinv for the final hop (+bias).
__global__ void k_hop(const float* __restrict__ xin, float* __restrict__ xout,
                      const int* __restrict__ off, const int* __restrict__ counts,
                      const float* __restrict__ dinv,
                      const int* __restrict__ col,
                      const float* __restrict__ bc, int finalHop, int N) {
    int gtid = blockIdx.x * blockDim.x + threadIdx.x;
    int node = gtid >> 6;
    int lane = threadIdx.x & 63;
    if (node >= N) return;
    int l = lane < DIMO ? lane : DIMO - 1;
    float di = dinv[node];
    float scale = finalHop ? di : di * di;
    int rs = off[node];
    int cnt = counts[node];
    float acc = xin[(long)node * DIMO + l];  // self loop, weight 1 in u-space
    for (int e = 0; e < cnt; e++) {
        int c = col[rs + e];
        acc += xin[(long)c * DIMO + l];
    }
    if (lane < DIMO) {
        float r = scale * acc;
        if (finalHop) r += bc[lane];
        xout[(long)node * DIMO + lane] = r;
    }
}

// ---------------- launch ----------------

extern "C" void kernel_launch(void* const* d_in, const int* in_sizes, int n_in,
                              void* d_out, int out_size, void* d_ws, size_t ws_size,
                              hipStream_t stream) {
    const float* x     = (const float*)d_in[0];
    const int*   ei    = (const int*)d_in[1];
    const float* Wsgc  = (const float*)d_in[2];
    const float* bsgc  = (const float*)d_in[3];
    const float* Whead = (const float*)d_in[4];
    const float* bhead = (const float*)d_in[5];
    float* out = (float*)d_out;

    const int N = in_sizes[0] / DIMI;
    const int E = in_sizes[1] / 2;
    const int* src = ei;
    const int* dst = ei + E;

    // carve workspace (256B-aligned chunks; never assume adjacency!)
    char* w = (char*)d_ws;
    auto carve = [&](size_t bytes) {
        char* p = w;
        w += (bytes + 255) & ~(size_t)255;
        return p;
    };
    int*   counts  = (int*)  carve((size_t)N * 4);
    int*   cursor  = (int*)  carve((size_t)N * 4);
    int*   off     = (int*)  carve((size_t)N * 4);
    float* dinv    = (float*)carve((size_t)N * 4);
    int*   partial = (int*)  carve(1024 * 4);
    int*   col     = (int*)  carve((size_t)E * 4);
    float* Wc      = (float*)carve(DIMI * DIMO * 4);
    float* bc      = (float*)carve(DIMO * 4);
    float* xA      = (float*)carve((size_t)N * DIMO * 4);

    const int B = 256;
    int nbN = (N + B - 1) / B;
    int nbE = (E + B - 1) / B;

    // CSR build
    k_zero<<<nbN, B, 0, stream>>>(counts, N);
    k_zero<<<nbN, B, 0, stream>>>(cursor, N);
    k_hist<<<nbE, B, 0, stream>>>(dst, counts, E);
    k_dinv<<<nbN, B, 0, stream>>>(counts, dinv, N);
    k_block_sums<<<nbN, B, 0, stream>>>(counts, partial, N);
    k_scan_partials<<<1, 1024, 0, stream>>>(partial, nbN);
    k_scan_final<<<nbN, B, 0, stream>>>(counts, partial, off, N);
    k_scatter<<<nbE, B, 0, stream>>>(src, dst, off, cursor, col, E);

    // fused weights + projection to 40 dims (with dinv pre-scale)
    k_wc<<<1, 256, 0, stream>>>(Wsgc, bsgc, Whead, bhead, Wc, bc);
    k_proj<<<(N + 31) / 32, 256, 0, stream>>>(x, Wc, dinv, xA, N);

    // 3 hops in u-space: xA -> out -> xA -> out(final: dinv scale + bias)
    int hopBlocks = (N * 64 + B - 1) / B;
    k_hop<<<hopBlocks, B, 0, stream>>>(xA, out, off, counts, dinv, col, bc, 0, N);
    k_hop<<<hopBlocks, B, 0, stream>>>(out, xA, off, counts, dinv, col, bc, 0, N);
    k_hop<<<hopBlocks, B, 0, stream>>>(xA, out, off, counts, dinv, col, bc, 1, N);
}

// Round 3
// 389.210 us; speedup vs baseline: 1.7043x; 1.7043x over previous
//
#include <hip/hip_runtime.h>
#include <hip/hip_bf16.h>

#define DIMI 64
#define DIMO 40

// ---------------- utility kernels ----------------

__global__ void k_zero2(int* __restrict__ a, int* __restrict__ b, int n) {
    int i = blockIdx.x * blockDim.x + threadIdx.x;
    if (i < n) { a[i] = 0; b[i] = 0; }
}

__global__ void k_hist(const int* __restrict__ dst, int* __restrict__ counts, int E) {
    int i = blockIdx.x * blockDim.x + threadIdx.x;
    if (i < E) atomicAdd(&counts[dst[i]], 1);
}

// per-block sums of counts -> partial[block]
__global__ void k_block_sums(const int* __restrict__ counts, int* __restrict__ partial, int n) {
    __shared__ int s[256];
    int i = blockIdx.x * 256 + threadIdx.x;
    s[threadIdx.x] = (i < n) ? counts[i] : 0;
    __syncthreads();
    for (int st = 128; st > 0; st >>= 1) {
        if (threadIdx.x < st) s[threadIdx.x] += s[threadIdx.x + st];
        __syncthreads();
    }
    if (threadIdx.x == 0) partial[blockIdx.x] = s[0];
}

// single block, 1024 threads: exclusive scan of partial[0..nb)
__global__ void k_scan_partials(int* partial, int nb) {
    __shared__ int s[1024];
    int t = threadIdx.x;
    int orig = (t < nb) ? partial[t] : 0;
    s[t] = orig;
    __syncthreads();
    for (int o = 1; o < 1024; o <<= 1) {
        int v = (t >= o) ? s[t - o] : 0;
        __syncthreads();
        s[t] += v;
        __syncthreads();
    }
    if (t < nb) partial[t] = s[t] - orig;  // exclusive
}

// block-local exclusive scan + partial offset -> off[i]; also dinv = rsqrt(deg+1)
__global__ void k_scan_final(const int* __restrict__ counts, const int* __restrict__ partial,
                             int* __restrict__ off, float* __restrict__ dinv, int n) {
    __shared__ int s[256];
    int t = threadIdx.x;
    int i = blockIdx.x * 256 + t;
    int orig = (i < n) ? counts[i] : 0;
    s[t] = orig;
    __syncthreads();
    for (int o = 1; o < 256; o <<= 1) {
        int v = (t >= o) ? s[t - o] : 0;
        __syncthreads();
        s[t] += v;
        __syncthreads();
    }
    if (i < n) {
        off[i] = s[t] - orig + partial[blockIdx.x];
        dinv[i] = rsqrtf((float)(orig + 1));
    }
}

__global__ void k_scatter(const int* __restrict__ src, const int* __restrict__ dst,
                          const int* __restrict__ off, int* __restrict__ cursor,
                          int* __restrict__ col, int E) {
    int i = blockIdx.x * blockDim.x + threadIdx.x;
    if (i < E) {
        int d = dst[i];
        int p = off[d] + atomicAdd(&cursor[d], 1);
        col[p] = src[i];
    }
}

// Wc = W_sgc @ W_head (64x40); bc = b_sgc @ W_head + b_head (40)
__global__ void k_wc(const float* __restrict__ Wsgc, const float* __restrict__ bsgc,
                     const float* __restrict__ Whead, const float* __restrict__ bhead,
                     float* __restrict__ Wc, float* __restrict__ bc) {
    __shared__ float sA[DIMI * DIMI];
    __shared__ float sB[DIMI * DIMO];
    int t = threadIdx.x;
    for (int i = t; i < DIMI * DIMI; i += 256) sA[i] = Wsgc[i];
    for (int i = t; i < DIMI * DIMO; i += 256) sB[i] = Whead[i];
    __syncthreads();
    for (int o = t; o < DIMI * DIMO; o += 256) {
        int k = o / DIMO, j = o % DIMO;
        float acc = 0.f;
        #pragma unroll
        for (int m = 0; m < DIMI; m++) acc += sA[k * DIMI + m] * sB[m * DIMO + j];
        Wc[o] = acc;
    }
    if (t < DIMO) {
        float acc = bhead[t];
        #pragma unroll
        for (int m = 0; m < DIMI; m++) acc += bsgc[m] * sB[m * DIMO + t];
        bc[t] = acc;
    }
}

// y[N,40] = dinv[n] * (x[N,64] @ Wc[64,40])   (u0 = D^{-1/2} x Wc)
__global__ void k_proj(const float* __restrict__ x, const float* __restrict__ Wc,
                       const float* __restrict__ dinv, float* __restrict__ y, int N) {
    __shared__ float sX[32 * DIMI];
    __shared__ float sW[DIMI * DIMO];
    int t = threadIdx.x;
    int n0 = blockIdx.x * 32;
    for (int i = t; i < DIMI * DIMO; i += 256) sW[i] = Wc[i];
    // 32 rows x 64 floats = 512 float4; 256 threads x 2
    const float4* x4 = (const float4*)x;
    float4* sX4 = (float4*)sX;
    for (int i = t; i < 32 * (DIMI / 4); i += 256) {
        int r = n0 + i / (DIMI / 4);
        sX4[i] = (r < N) ? x4[(long)r * (DIMI / 4) + (i & (DIMI / 4 - 1))]
                         : make_float4(0.f, 0.f, 0.f, 0.f);
    }
    __syncthreads();
    for (int o = t; o < 32 * DIMO; o += 256) {
        int li = o / DIMO, j = o % DIMO;
        int node = n0 + li;
        if (node < N) {
            float acc = 0.f;
            #pragma unroll
            for (int k = 0; k < DIMI; k++) acc += sX[li * DIMI + k] * sW[k * DIMO + j];
            y[(long)node * DIMO + j] = dinv[node] * acc;
        }
    }
}

// one 64-lane wave per node; lane = feature (lanes 40..63 duplicate lane 39).
// u-space hop: out = scale * ( sum_{nbr} in[nbr] + in[self] )
// scale = dinv^2 for intermediate hops, dinv for the final hop (+bias).
// Latency fix: coalesced col preload (lane e holds col[rs+e]) + shfl broadcast,
// 8-wide hand-unrolled gather batches so 8 loads are in flight per wave.
__global__ void k_hop(const float* __restrict__ xin, float* __restrict__ xout,
                      const int* __restrict__ off, const int* __restrict__ counts,
                      const float* __restrict__ dinv,
                      const int* __restrict__ col,
                      const float* __restrict__ bc, int finalHop, int N) {
    int gtid = blockIdx.x * blockDim.x + threadIdx.x;
    int node = gtid >> 6;
    int lane = threadIdx.x & 63;
    if (node >= N) return;
    int l = lane < DIMO ? lane : DIMO - 1;
    int rs = off[node];
    int cnt = counts[node];
    // coalesced preload of up to 64 neighbor indices (one load per lane)
    int cidx = (lane < cnt) ? col[rs + lane] : node;
    float acc = xin[(long)node * DIMO + l];  // self loop (weight 1 in u-space)
    int cmain = cnt < 64 ? cnt : 64;
    int e = 0;
    for (; e + 8 <= cmain; e += 8) {
        int c0 = __shfl(cidx, e + 0, 64);
        int c1 = __shfl(cidx, e + 1, 64);
        int c2 = __shfl(cidx, e + 2, 64);
        int c3 = __shfl(cidx, e + 3, 64);
        int c4 = __shfl(cidx, e + 4, 64);
        int c5 = __shfl(cidx, e + 5, 64);
        int c6 = __shfl(cidx, e + 6, 64);
        int c7 = __shfl(cidx, e + 7, 64);
        float v0 = xin[(long)c0 * DIMO + l];
        float v1 = xin[(long)c1 * DIMO + l];
        float v2 = xin[(long)c2 * DIMO + l];
        float v3 = xin[(long)c3 * DIMO + l];
        float v4 = xin[(long)c4 * DIMO + l];
        float v5 = xin[(long)c5 * DIMO + l];
        float v6 = xin[(long)c6 * DIMO + l];
        float v7 = xin[(long)c7 * DIMO + l];
        acc += ((v0 + v1) + (v2 + v3)) + ((v4 + v5) + (v6 + v7));
    }
    for (; e < cmain; e++) {
        int c = __shfl(cidx, e, 64);
        acc += xin[(long)c * DIMO + l];
    }
    for (int e2 = 64; e2 < cnt; e2++) {  // vanishingly rare (deg>64)
        int c = col[rs + e2];
        acc += xin[(long)c * DIMO + l];
    }
    float di = dinv[node];
    float scale = finalHop ? di : di * di;
    if (lane < DIMO) {
        float r = scale * acc;
        if (finalHop) r += bc[lane];
        xout[(long)node * DIMO + lane] = r;
    }
}

// ---------------- launch ----------------

extern "C" void kernel_launch(void* const* d_in, const int* in_sizes, int n_in,
                              void* d_out, int out_size, void* d_ws, size_t ws_size,
                              hipStream_t stream) {
    const float* x     = (const float*)d_in[0];
    const int*   ei    = (const int*)d_in[1];
    const float* Wsgc  = (const float*)d_in[2];
    const float* bsgc  = (const float*)d_in[3];
    const float* Whead = (const float*)d_in[4];
    const float* bhead = (const float*)d_in[5];
    float* out = (float*)d_out;

    const int N = in_sizes[0] / DIMI;
    const int E = in_sizes[1] / 2;
    const int* src = ei;
    const int* dst = ei + E;

    // carve workspace (256B-aligned chunks; never assume adjacency!)
    char* w = (char*)d_ws;
    auto carve = [&](size_t bytes) {
        char* p = w;
        w += (bytes + 255) & ~(size_t)255;
        return p;
    };
    int*   counts  = (int*)  carve((size_t)N * 4);
    int*   cursor  = (int*)  carve((size_t)N * 4);
    int*   off     = (int*)  carve((size_t)N * 4);
    float* dinv    = (float*)carve((size_t)N * 4);
    int*   partial = (int*)  carve(1024 * 4);
    int*   col     = (int*)  carve((size_t)E * 4);
    float* Wc      = (float*)carve(DIMI * DIMO * 4);
    float* bc      = (float*)carve(DIMO * 4);
    float* xA      = (float*)carve((size_t)N * DIMO * 4);

    const int B = 256;
    int nbN = (N + B - 1) / B;
    int nbE = (E + B - 1) / B;

    // CSR build
    k_zero2<<<nbN, B, 0, stream>>>(counts, cursor, N);
    k_hist<<<nbE, B, 0, stream>>>(dst, counts, E);
    k_block_sums<<<nbN, B, 0, stream>>>(counts, partial, N);
    k_scan_partials<<<1, 1024, 0, stream>>>(partial, nbN);
    k_scan_final<<<nbN, B, 0, stream>>>(counts, partial, off, dinv, N);
    k_scatter<<<nbE, B, 0, stream>>>(src, dst, off, cursor, col, E);

    // fused weights + projection to 40 dims (with dinv pre-scale)
    k_wc<<<1, 256, 0, stream>>>(Wsgc, bsgc, Whead, bhead, Wc, bc);
    k_proj<<<(N + 31) / 32, 256, 0, stream>>>(x, Wc, dinv, xA, N);

    // 3 hops in u-space: xA -> out -> xA -> out(final: dinv scale + bias)
    int hopBlocks = (N * 64 + B - 1) / B;
    k_hop<<<hopBlocks, B, 0, stream>>>(xA, out, off, counts, dinv, col, bc, 0, N);
    k_hop<<<hopBlocks, B, 0, stream>>>(out, xA, off, counts, dinv, col, bc, 0, N);
    k_hop<<<hopBlocks, B, 0, stream>>>(xA, out, off, counts, dinv, col, bc, 1, N);
}

// Round 4
// 288.073 us; speedup vs baseline: 2.3027x; 1.3511x over previous
//
#include <hip/hip_runtime.h>
#include <hip/hip_bf16.h>

#define DIMI 64
#define DIMO 40

#define NPB_SHIFT 6
#define NPB 64            // dst-nodes per bucket
#define BCAP 1280         // bucket capacity (mean 1024, +8 sigma)
#define MAXNB 1600        // >= ceil(N/NPB) = 1563
#define CHUNK 8192        // edges per bucketA block

// ---------------- CSR build: bucketed (dense-write) path ----------------

__global__ void k_zero(int* __restrict__ p, int n) {
    int i = blockIdx.x * blockDim.x + threadIdx.x;
    if (i < n) p[i] = 0;
}

// Phase A: bin edges into buckets of NPB dst-nodes; block-owned dense runs.
__global__ void k_bucketA(const int* __restrict__ src, const int* __restrict__ dst,
                          int* __restrict__ bcnt, int* __restrict__ ebD,
                          int* __restrict__ ebS, int E, int nbk) {
    __shared__ int lh[MAXNB];  // hist -> run base
    __shared__ int lr[MAXNB];  // running offset within run
    int t = threadIdx.x;
    int e0 = blockIdx.x * CHUNK;
    int e1 = min(e0 + CHUNK, E);
    for (int i = t; i < nbk; i += 256) lh[i] = 0;
    __syncthreads();
    for (int i = e0 + t; i < e1; i += 256)
        atomicAdd(&lh[dst[i] >> NPB_SHIFT], 1);
    __syncthreads();
    for (int i = t; i < nbk; i += 256) {
        int c = lh[i];
        lh[i] = c ? atomicAdd(&bcnt[i], c) : 0;  // reserve dense run
        lr[i] = 0;
    }
    __syncthreads();
    for (int i = e0 + t; i < e1; i += 256) {
        int d = dst[i];
        int b = d >> NPB_SHIFT;
        int slot = lh[b] + atomicAdd(&lr[b], 1);
        if (slot < BCAP) {
            ebD[b * BCAP + slot] = d;
            ebS[b * BCAP + slot] = src[i];
        }
    }
}

// Phase B: per-bucket node counts in LDS -> dense non-atomic counts write.
__global__ void k_bucketB(const int* __restrict__ bcnt, const int* __restrict__ ebD,
                          int* __restrict__ counts, int N) {
    __shared__ int lh[NPB];
    int b = blockIdx.x, t = threadIdx.x;
    if (t < NPB) lh[t] = 0;
    __syncthreads();
    int n = min(bcnt[b], BCAP);
    int base = b * BCAP;
    for (int i = t; i < n; i += 256)
        atomicAdd(&lh[ebD[base + i] & (NPB - 1)], 1);
    __syncthreads();
    int d = (b << NPB_SHIFT) + t;
    if (t < NPB && d < N) counts[d] = lh[t];
}

// Phase C: per-bucket LDS scatter + fully-coalesced col segment writeout.
__global__ void k_bucketC(const int* __restrict__ bcnt, const int* __restrict__ ebD,
                          const int* __restrict__ ebS, const int* __restrict__ off,
                          int* __restrict__ col, int N, int E) {
    __shared__ int loff[NPB];
    __shared__ int lc[NPB];
    __shared__ int scol[BCAP];
    int b = blockIdx.x, t = threadIdx.x;
    int d0 = b << NPB_SHIFT;
    if (t < NPB) {
        int d = d0 + t;
        loff[t] = (d < N) ? off[d] : E;
        lc[t] = 0;
    }
    __syncthreads();
    int n = min(bcnt[b], BCAP);
    int base = b * BCAP;
    int o0 = loff[0];
    for (int i = t; i < n; i += 256) {
        int d = ebD[base + i];
        int lp = atomicAdd(&lc[d & (NPB - 1)], 1);
        int idx = loff[d & (NPB - 1)] - o0 + lp;
        if (idx < BCAP) scol[idx] = ebS[base + i];
    }
    __syncthreads();
    for (int i = t; i < n; i += 256) col[o0 + i] = scol[i];
}

// ---------------- CSR build: fallback (random-write) path ----------------

__global__ void k_hist(const int* __restrict__ dst, int* __restrict__ counts, int E) {
    int i = blockIdx.x * blockDim.x + threadIdx.x;
    if (i < E) atomicAdd(&counts[dst[i]], 1);
}

__global__ void k_scatter(const int* __restrict__ src, const int* __restrict__ dst,
                          const int* __restrict__ off, int* __restrict__ cursor,
                          int* __restrict__ col, int E) {
    int i = blockIdx.x * blockDim.x + threadIdx.x;
    if (i < E) {
        int d = dst[i];
        int p = off[d] + atomicAdd(&cursor[d], 1);
        col[p] = src[i];
    }
}

// ---------------- scan ----------------

__global__ void k_block_sums(const int* __restrict__ counts, int* __restrict__ partial, int n) {
    __shared__ int s[256];
    int i = blockIdx.x * 256 + threadIdx.x;
    s[threadIdx.x] = (i < n) ? counts[i] : 0;
    __syncthreads();
    for (int st = 128; st > 0; st >>= 1) {
        if (threadIdx.x < st) s[threadIdx.x] += s[threadIdx.x + st];
        __syncthreads();
    }
    if (threadIdx.x == 0) partial[blockIdx.x] = s[0];
}

__global__ void k_scan_partials(int* partial, int nb) {
    __shared__ int s[1024];
    int t = threadIdx.x;
    int orig = (t < nb) ? partial[t] : 0;
    s[t] = orig;
    __syncthreads();
    for (int o = 1; o < 1024; o <<= 1) {
        int v = (t >= o) ? s[t - o] : 0;
        __syncthreads();
        s[t] += v;
        __syncthreads();
    }
    if (t < nb) partial[t] = s[t] - orig;  // exclusive
}

// block-local exclusive scan + partial offset -> off[i]; also dinv = rsqrt(deg+1)
__global__ void k_scan_final(const int* __restrict__ counts, const int* __restrict__ partial,
                             int* __restrict__ off, float* __restrict__ dinv, int n) {
    __shared__ int s[256];
    int t = threadIdx.x;
    int i = blockIdx.x * 256 + t;
    int orig = (i < n) ? counts[i] : 0;
    s[t] = orig;
    __syncthreads();
    for (int o = 1; o < 256; o <<= 1) {
        int v = (t >= o) ? s[t - o] : 0;
        __syncthreads();
        s[t] += v;
        __syncthreads();
    }
    if (i < n) {
        off[i] = s[t] - orig + partial[blockIdx.x];
        dinv[i] = rsqrtf((float)(orig + 1));
    }
}

// ---------------- dense math ----------------

// Wc = W_sgc @ W_head (64x40); bc = b_sgc @ W_head + b_head (40)
__global__ void k_wc(const float* __restrict__ Wsgc, const float* __restrict__ bsgc,
                     const float* __restrict__ Whead, const float* __restrict__ bhead,
                     float* __restrict__ Wc, float* __restrict__ bc) {
    __shared__ float sA[DIMI * DIMI];
    __shared__ float sB[DIMI * DIMO];
    int t = threadIdx.x;
    for (int i = t; i < DIMI * DIMI; i += 256) sA[i] = Wsgc[i];
    for (int i = t; i < DIMI * DIMO; i += 256) sB[i] = Whead[i];
    __syncthreads();
    for (int o = t; o < DIMI * DIMO; o += 256) {
        int k = o / DIMO, j = o % DIMO;
        float acc = 0.f;
        #pragma unroll
        for (int m = 0; m < DIMI; m++) acc += sA[k * DIMI + m] * sB[m * DIMO + j];
        Wc[o] = acc;
    }
    if (t < DIMO) {
        float acc = bhead[t];
        #pragma unroll
        for (int m = 0; m < DIMI; m++) acc += bsgc[m] * sB[m * DIMO + t];
        bc[t] = acc;
    }
}

// y[N,40] = dinv[n] * (x[N,64] @ Wc[64,40])   (u0 = D^{-1/2} x Wc)
__global__ void k_proj(const float* __restrict__ x, const float* __restrict__ Wc,
                       const float* __restrict__ dinv, float* __restrict__ y, int N) {
    __shared__ float sX[32 * DIMI];
    __shared__ float sW[DIMI * DIMO];
    int t = threadIdx.x;
    int n0 = blockIdx.x * 32;
    for (int i = t; i < DIMI * DIMO; i += 256) sW[i] = Wc[i];
    const float4* x4 = (const float4*)x;
    float4* sX4 = (float4*)sX;
    for (int i = t; i < 32 * (DIMI / 4); i += 256) {
        int r = n0 + i / (DIMI / 4);
        sX4[i] = (r < N) ? x4[(long)r * (DIMI / 4) + (i & (DIMI / 4 - 1))]
                         : make_float4(0.f, 0.f, 0.f, 0.f);
    }
    __syncthreads();
    for (int o = t; o < 32 * DIMO; o += 256) {
        int li = o / DIMO, j = o % DIMO;
        int node = n0 + li;
        if (node < N) {
            float acc = 0.f;
            #pragma unroll
            for (int k = 0; k < DIMI; k++) acc += sX[li * DIMI + k] * sW[k * DIMO + j];
            y[(long)node * DIMO + j] = dinv[node] * acc;
        }
    }
}

// one 64-lane wave per node; lane = feature (lanes 40..63 duplicate lane 39).
// u-space hop: out = scale * ( sum_{nbr} in[nbr] + in[self] )
// 16 gathers in flight per wave to hide L2/L3 latency.
__global__ void k_hop(const float* __restrict__ xin, float* __restrict__ xout,
                      const int* __restrict__ off, const int* __restrict__ counts,
                      const float* __restrict__ dinv,
                      const int* __restrict__ col,
                      const float* __restrict__ bc, int finalHop, int N) {
    int gtid = blockIdx.x * blockDim.x + threadIdx.x;
    int node = gtid >> 6;
    int lane = threadIdx.x & 63;
    if (node >= N) return;
    int l = lane < DIMO ? lane : DIMO - 1;
    int rs = off[node];
    int cnt = counts[node];
    int cidx = (lane < cnt) ? col[rs + lane] : node;  // coalesced preload
    float acc = xin[(long)node * DIMO + l];           // self loop
    int cmain = cnt < 64 ? cnt : 64;
    int e = 0;
    for (; e + 16 <= cmain; e += 16) {
        float v[16];
        #pragma unroll
        for (int u = 0; u < 16; u++) {
            int c = __shfl(cidx, e + u, 64);
            v[u] = xin[(long)c * DIMO + l];
        }
        float s01 = (v[0] + v[1]) + (v[2] + v[3]);
        float s23 = (v[4] + v[5]) + (v[6] + v[7]);
        float s45 = (v[8] + v[9]) + (v[10] + v[11]);
        float s67 = (v[12] + v[13]) + (v[14] + v[15]);
        acc += (s01 + s23) + (s45 + s67);
    }
    for (; e + 4 <= cmain; e += 4) {
        float v[4];
        #pragma unroll
        for (int u = 0; u < 4; u++) {
            int c = __shfl(cidx, e + u, 64);
            v[u] = xin[(long)c * DIMO + l];
        }
        acc += (v[0] + v[1]) + (v[2] + v[3]);
    }
    for (; e < cmain; e++) {
        int c = __shfl(cidx, e, 64);
        acc += xin[(long)c * DIMO + l];
    }
    for (int e2 = 64; e2 < cnt; e2++) {  // deg>64: vanishingly rare
        acc += xin[(long)col[rs + e2] * DIMO + l];
    }
    float di = dinv[node];
    float scale = finalHop ? di : di * di;
    if (lane < DIMO) {
        float r = scale * acc;
        if (finalHop) r += bc[lane];
        xout[(long)node * DIMO + lane] = r;
    }
}

// ---------------- launch ----------------

extern "C" void kernel_launch(void* const* d_in, const int* in_sizes, int n_in,
                              void* d_out, int out_size, void* d_ws, size_t ws_size,
                              hipStream_t stream) {
    const float* x     = (const float*)d_in[0];
    const int*   ei    = (const int*)d_in[1];
    const float* Wsgc  = (const float*)d_in[2];
    const float* bsgc  = (const float*)d_in[3];
    const float* Whead = (const float*)d_in[4];
    const float* bhead = (const float*)d_in[5];
    float* out = (float*)d_out;

    const int N = in_sizes[0] / DIMI;
    const int E = in_sizes[1] / 2;
    const int* src = ei;
    const int* dst = ei + E;
    const int nbk = (N + NPB - 1) >> NPB_SHIFT;  // buckets

    // carve workspace (256B-aligned chunks)
    char* w = (char*)d_ws;
    auto carve = [&](size_t bytes) {
        char* p = w;
        w += (bytes + 255) & ~(size_t)255;
        return p;
    };
    int*   counts  = (int*)  carve((size_t)N * 4);
    int*   cursor  = (int*)  carve((size_t)N * 4);
    int*   off     = (int*)  carve((size_t)N * 4);
    float* dinv    = (float*)carve((size_t)N * 4);
    int*   partial = (int*)  carve(1024 * 4);
    int*   col     = (int*)  carve((size_t)E * 4);
    float* Wc      = (float*)carve(DIMI * DIMO * 4);
    float* bc      = (float*)carve(DIMO * 4);
    float* xA      = (float*)carve((size_t)N * DIMO * 4);
    size_t base_need = (size_t)(w - (char*)d_ws);
    int*   bcnt    = (int*)  carve((size_t)nbk * 4);
    int*   ebD     = (int*)  carve((size_t)nbk * BCAP * 4);
    int*   ebS     = (int*)  carve((size_t)nbk * BCAP * 4);
    size_t bucket_need = (size_t)(w - (char*)d_ws);
    const bool useBuckets = (ws_size >= bucket_need) && (nbk <= MAXNB);
    (void)base_need;

    const int B = 256;
    int nbN = (N + B - 1) / B;
    int nbE = (E + B - 1) / B;

    if (useBuckets) {
        // dense-write CSR build: bin -> count -> scan -> place
        k_zero<<<(nbk + B - 1) / B, B, 0, stream>>>(bcnt, nbk);
        int nbA = (E + CHUNK - 1) / CHUNK;
        k_bucketA<<<nbA, B, 0, stream>>>(src, dst, bcnt, ebD, ebS, E, nbk);
        k_bucketB<<<nbk, B, 0, stream>>>(bcnt, ebD, counts, N);
        k_block_sums<<<nbN, B, 0, stream>>>(counts, partial, N);
        k_scan_partials<<<1, 1024, 0, stream>>>(partial, nbN);
        k_scan_final<<<nbN, B, 0, stream>>>(counts, partial, off, dinv, N);
        k_bucketC<<<nbk, B, 0, stream>>>(bcnt, ebD, ebS, off, col, N, E);
    } else {
        // fallback: random-write CSR build
        k_zero<<<nbN, B, 0, stream>>>(counts, N);
        k_zero<<<nbN, B, 0, stream>>>(cursor, N);
        k_hist<<<nbE, B, 0, stream>>>(dst, counts, E);
        k_block_sums<<<nbN, B, 0, stream>>>(counts, partial, N);
        k_scan_partials<<<1, 1024, 0, stream>>>(partial, nbN);
        k_scan_final<<<nbN, B, 0, stream>>>(counts, partial, off, dinv, N);
        k_scatter<<<nbE, B, 0, stream>>>(src, dst, off, cursor, col, E);
    }

    // fused weights + projection to 40 dims (with dinv pre-scale)
    k_wc<<<1, 256, 0, stream>>>(Wsgc, bsgc, Whead, bhead, Wc, bc);
    k_proj<<<(N + 31) / 32, 256, 0, stream>>>(x, Wc, dinv, xA, N);

    // 3 hops in u-space: xA -> out -> xA -> out(final: dinv scale + bias)
    int hopBlocks = (N * 64 + B - 1) / B;
    k_hop<<<hopBlocks, B, 0, stream>>>(xA, out, off, counts, dinv, col, bc, 0, N);
    k_hop<<<hopBlocks, B, 0, stream>>>(out, xA, off, counts, dinv, col, bc, 0, N);
    k_hop<<<hopBlocks, B, 0, stream>>>(xA, out, off, counts, dinv, col, bc, 1, N);
}

// Round 5
// 252.796 us; speedup vs baseline: 2.6240x; 1.1395x over previous
//
#include <hip/hip_runtime.h>
#include <hip/hip_bf16.h>
#include <hip/hip_fp16.h>

#define DIMI 64
#define DIMO 40
#define PADO 64           // fp16 row stride (128B = 2 cache lines)

#define NBK_SHIFT 9
#define NPBK 512          // dst-nodes per bucket
#define NBKMAX 256
#define BCAP 9216         // bucket capacity (mean 8192, +11 sigma)
#define CHUNK 4096        // edges per binA block

// ---------------- CSR build: LDS-sorted counting-sort path ----------------

__global__ void k_zero(int* __restrict__ p, int n) {
    int i = blockIdx.x * blockDim.x + threadIdx.x;
    if (i < n) p[i] = 0;
}

// Phase A: bin CHUNK edges into 512-node buckets; LDS-sort; coalesced writeout.
__global__ void k_binA(const int* __restrict__ src, const int* __restrict__ dst,
                       int* __restrict__ bcnt, int2* __restrict__ ebDS,
                       int E, int nbk) {
    __shared__ int h[NBKMAX];   // hist -> inclusive scan
    __shared__ int lb[NBKMAX];  // local exclusive base
    __shared__ int lc[NBKMAX];  // local cursor
    __shared__ int gb[NBKMAX];  // global run base (within bucket)
    __shared__ int2 eb[CHUNK];  // LDS-sorted (d,s) records
    int t = threadIdx.x;
    int e0 = blockIdx.x * CHUNK;
    int e1 = min(e0 + CHUNK, E);
    int nE = e1 - e0;
    h[t] = 0;
    __syncthreads();
    int d[CHUNK / 256], s[CHUNK / 256];
    #pragma unroll
    for (int u = 0; u < CHUNK / 256; u++) {
        int idx = e0 + t + u * 256;
        if (idx < e1) {
            d[u] = dst[idx];
            s[u] = src[idx];
            atomicAdd(&h[d[u] >> NBK_SHIFT], 1);
        }
    }
    __syncthreads();
    int orig = h[t];
    for (int o = 1; o < 256; o <<= 1) {   // inclusive Hillis-Steele scan
        int v = (t >= o) ? h[t - o] : 0;
        __syncthreads();
        h[t] += v;
        __syncthreads();
    }
    lb[t] = h[t] - orig;
    lc[t] = 0;
    gb[t] = orig ? atomicAdd(&bcnt[t], orig) : 0;  // reserve dense global run
    __syncthreads();
    #pragma unroll
    for (int u = 0; u < CHUNK / 256; u++) {
        int idx = e0 + t + u * 256;
        if (idx < e1) {
            int b = d[u] >> NBK_SHIFT;
            int r = atomicAdd(&lc[b], 1);
            eb[lb[b] + r] = make_int2(d[u], s[u]);
        }
    }
    __syncthreads();
    // linear readout: consecutive i in a run -> consecutive global slots
    for (int i = t; i < nE; i += 256) {
        int2 e = eb[i];
        int b = e.x >> NBK_SHIFT;
        int slot = gb[b] + (i - lb[b]);
        if (slot < BCAP) ebDS[(size_t)b * BCAP + slot] = e;
    }
}

// Phase B: per-bucket node counts via LDS hist -> dense counts write.
__global__ void k_binB(const int* __restrict__ bcnt, const int2* __restrict__ ebDS,
                       int* __restrict__ counts, int N) {
    __shared__ int lh[NPBK];
    int b = blockIdx.x, t = threadIdx.x;
    for (int j = t; j < NPBK; j += 256) lh[j] = 0;
    __syncthreads();
    int n = min(bcnt[b], BCAP);
    size_t base = (size_t)b * BCAP;
    for (int i = t; i < n; i += 256)
        atomicAdd(&lh[ebDS[base + i].x & (NPBK - 1)], 1);
    __syncthreads();
    int d0 = b << NBK_SHIFT;
    for (int j = t; j < NPBK; j += 256) {
        int dd = d0 + j;
        if (dd < N) counts[dd] = lh[j];
    }
}

// Phase C: per-bucket LDS scatter + dense coalesced col segment writeout.
__global__ void k_binC(const int* __restrict__ bcnt, const int2* __restrict__ ebDS,
                       const int* __restrict__ off, int* __restrict__ col,
                       int N, int E) {
    __shared__ int loff[NPBK];
    __shared__ int lc[NPBK];
    __shared__ int scol[BCAP];
    int b = blockIdx.x, t = threadIdx.x;
    int d0 = b << NBK_SHIFT;
    for (int j = t; j < NPBK; j += 256) {
        int dd = d0 + j;
        loff[j] = (dd < N) ? off[dd] : E;
        lc[j] = 0;
    }
    __syncthreads();
    int n = min(bcnt[b], BCAP);
    size_t base = (size_t)b * BCAP;
    int o0 = loff[0];
    for (int i = t; i < n; i += 256) {
        int2 e = ebDS[base + i];
        int local = e.x & (NPBK - 1);
        int r = atomicAdd(&lc[local], 1);
        int idx = loff[local] - o0 + r;
        if (idx < BCAP) scol[idx] = e.y;
    }
    __syncthreads();
    for (int i = t; i < n; i += 256) col[o0 + i] = scol[i];
}

// ---------------- CSR build: fallback (random-write) path ----------------

__global__ void k_hist(const int* __restrict__ dst, int* __restrict__ counts, int E) {
    int i = blockIdx.x * blockDim.x + threadIdx.x;
    if (i < E) atomicAdd(&counts[dst[i]], 1);
}

__global__ void k_scatter(const int* __restrict__ src, const int* __restrict__ dst,
                          const int* __restrict__ off, int* __restrict__ cursor,
                          int* __restrict__ col, int E) {
    int i = blockIdx.x * blockDim.x + threadIdx.x;
    if (i < E) {
        int d = dst[i];
        int p = off[d] + atomicAdd(&cursor[d], 1);
        col[p] = src[i];
    }
}

// ---------------- scan ----------------

__global__ void k_block_sums(const int* __restrict__ counts, int* __restrict__ partial, int n) {
    __shared__ int s[256];
    int i = blockIdx.x * 256 + threadIdx.x;
    s[threadIdx.x] = (i < n) ? counts[i] : 0;
    __syncthreads();
    for (int st = 128; st > 0; st >>= 1) {
        if (threadIdx.x < st) s[threadIdx.x] += s[threadIdx.x + st];
        __syncthreads();
    }
    if (threadIdx.x == 0) partial[blockIdx.x] = s[0];
}

__global__ void k_scan_partials(int* partial, int nb) {
    __shared__ int s[1024];
    int t = threadIdx.x;
    int orig = (t < nb) ? partial[t] : 0;
    s[t] = orig;
    __syncthreads();
    for (int o = 1; o < 1024; o <<= 1) {
        int v = (t >= o) ? s[t - o] : 0;
        __syncthreads();
        s[t] += v;
        __syncthreads();
    }
    if (t < nb) partial[t] = s[t] - orig;  // exclusive
}

__global__ void k_scan_final(const int* __restrict__ counts, const int* __restrict__ partial,
                             int* __restrict__ off, float* __restrict__ dinv, int n) {
    __shared__ int s[256];
    int t = threadIdx.x;
    int i = blockIdx.x * 256 + t;
    int orig = (i < n) ? counts[i] : 0;
    s[t] = orig;
    __syncthreads();
    for (int o = 1; o < 256; o <<= 1) {
        int v = (t >= o) ? s[t - o] : 0;
        __syncthreads();
        s[t] += v;
        __syncthreads();
    }
    if (i < n) {
        off[i] = s[t] - orig + partial[blockIdx.x];
        dinv[i] = rsqrtf((float)(orig + 1));
    }
}

// ---------------- dense math ----------------

__global__ void k_wc(const float* __restrict__ Wsgc, const float* __restrict__ bsgc,
                     const float* __restrict__ Whead, const float* __restrict__ bhead,
                     float* __restrict__ Wc, float* __restrict__ bc) {
    __shared__ float sA[DIMI * DIMI];
    __shared__ float sB[DIMI * DIMO];
    int t = threadIdx.x;
    for (int i = t; i < DIMI * DIMI; i += 256) sA[i] = Wsgc[i];
    for (int i = t; i < DIMI * DIMO; i += 256) sB[i] = Whead[i];
    __syncthreads();
    for (int o = t; o < DIMI * DIMO; o += 256) {
        int k = o / DIMO, j = o % DIMO;
        float acc = 0.f;
        #pragma unroll
        for (int m = 0; m < DIMI; m++) acc += sA[k * DIMI + m] * sB[m * DIMO + j];
        Wc[o] = acc;
    }
    if (t < DIMO) {
        float acc = bhead[t];
        #pragma unroll
        for (int m = 0; m < DIMI; m++) acc += bsgc[m] * sB[m * DIMO + t];
        bc[t] = acc;
    }
}

// y[N,PADO(fp16)] = dinv[n] * (x[N,64] @ Wc[64,40])
__global__ void k_proj(const float* __restrict__ x, const float* __restrict__ Wc,
                       const float* __restrict__ dinv, __half* __restrict__ y, int N) {
    __shared__ float sX[32 * DIMI];
    __shared__ float sW[DIMI * DIMO];
    int t = threadIdx.x;
    int n0 = blockIdx.x * 32;
    for (int i = t; i < DIMI * DIMO; i += 256) sW[i] = Wc[i];
    const float4* x4 = (const float4*)x;
    float4* sX4 = (float4*)sX;
    for (int i = t; i < 32 * (DIMI / 4); i += 256) {
        int r = n0 + i / (DIMI / 4);
        sX4[i] = (r < N) ? x4[(long)r * (DIMI / 4) + (i & (DIMI / 4 - 1))]
                         : make_float4(0.f, 0.f, 0.f, 0.f);
    }
    __syncthreads();
    for (int o = t; o < 32 * DIMO; o += 256) {
        int li = o / DIMO, j = o % DIMO;
        int node = n0 + li;
        if (node < N) {
            float acc = 0.f;
            #pragma unroll
            for (int k = 0; k < DIMI; k++) acc += sX[li * DIMI + k] * sW[k * DIMO + j];
            y[(long)node * PADO + j] = __float2half(dinv[node] * acc);
        }
    }
}

// one wave per node; lane = feature. fp16 rows padded to 128B (2 lines).
// u-space hop: out = scale * ( sum_{nbr} in[nbr] + in[self] )
__global__ void k_hop(const __half* __restrict__ xin, __half* __restrict__ xoutH,
                      float* __restrict__ outF,
                      const int* __restrict__ off, const int* __restrict__ counts,
                      const float* __restrict__ dinv,
                      const int* __restrict__ col,
                      const float* __restrict__ bc, int finalHop, int N) {
    int gtid = blockIdx.x * blockDim.x + threadIdx.x;
    int node = gtid >> 6;
    int lane = threadIdx.x & 63;
    if (node >= N) return;
    int l = lane < DIMO ? lane : DIMO - 1;
    int rs = off[node];
    int cnt = counts[node];
    int cidx = (lane < cnt) ? col[rs + lane] : node;  // coalesced preload
    float acc = __half2float(xin[(long)node * PADO + l]);  // self loop
    int cmain = cnt < 64 ? cnt : 64;
    int e = 0;
    for (; e + 16 <= cmain; e += 16) {
        float v[16];
        #pragma unroll
        for (int u = 0; u < 16; u++) {
            int c = __shfl(cidx, e + u, 64);
            v[u] = __half2float(xin[(long)c * PADO + l]);
        }
        float s01 = (v[0] + v[1]) + (v[2] + v[3]);
        float s23 = (v[4] + v[5]) + (v[6] + v[7]);
        float s45 = (v[8] + v[9]) + (v[10] + v[11]);
        float s67 = (v[12] + v[13]) + (v[14] + v[15]);
        acc += (s01 + s23) + (s45 + s67);
    }
    for (; e + 4 <= cmain; e += 4) {
        float v[4];
        #pragma unroll
        for (int u = 0; u < 4; u++) {
            int c = __shfl(cidx, e + u, 64);
            v[u] = __half2float(xin[(long)c * PADO + l]);
        }
        acc += (v[0] + v[1]) + (v[2] + v[3]);
    }
    for (; e < cmain; e++) {
        int c = __shfl(cidx, e, 64);
        acc += __half2float(xin[(long)c * PADO + l]);
    }
    for (int e2 = 64; e2 < cnt; e2++) {  // deg>64: vanishingly rare
        acc += __half2float(xin[(long)col[rs + e2] * PADO + l]);
    }
    float di = dinv[node];
    float scale = finalHop ? di : di * di;
    if (lane < DIMO) {
        float r = scale * acc;
        if (finalHop) outF[(long)node * DIMO + lane] = r + bc[lane];
        else xoutH[(long)node * PADO + lane] = __float2half(r);
    }
}

// ---------------- launch ----------------

extern "C" void kernel_launch(void* const* d_in, const int* in_sizes, int n_in,
                              void* d_out, int out_size, void* d_ws, size_t ws_size,
                              hipStream_t stream) {
    const float* x     = (const float*)d_in[0];
    const int*   ei    = (const int*)d_in[1];
    const float* Wsgc  = (const float*)d_in[2];
    const float* bsgc  = (const float*)d_in[3];
    const float* Whead = (const float*)d_in[4];
    const float* bhead = (const float*)d_in[5];
    float* out = (float*)d_out;

    const int N = in_sizes[0] / DIMI;
    const int E = in_sizes[1] / 2;
    const int* src = ei;
    const int* dst = ei + E;
    const int nbk = (N + NPBK - 1) >> NBK_SHIFT;

    // carve workspace (256B-aligned)
    char* w = (char*)d_ws;
    auto carve = [&](size_t bytes) {
        char* p = w;
        w += (bytes + 255) & ~(size_t)255;
        return p;
    };
    int*   counts  = (int*)  carve((size_t)N * 4);
    int*   cursor  = (int*)  carve((size_t)N * 4);
    int*   off     = (int*)  carve((size_t)N * 4);
    float* dinv    = (float*)carve((size_t)N * 4);
    int*   partial = (int*)  carve(1024 * 4);
    int*   col     = (int*)  carve((size_t)E * 4);
    float* Wc      = (float*)carve(DIMI * DIMO * 4);
    float* bc      = (float*)carve(DIMO * 4);
    int*   bcnt    = (int*)  carve((size_t)nbk * 4);
    // union region: ebDS (CSR staging, dead before k_proj) aliases xA+xB
    size_t xbytes  = (size_t)N * PADO * 2;
    size_t ebytes  = (size_t)nbk * BCAP * 8;
    size_t ubytes  = ebytes > 2 * xbytes ? ebytes : 2 * xbytes;
    char*  uni     = carve(ubytes);
    int2*   ebDS = (int2*)uni;
    __half* xA   = (__half*)uni;
    __half* xB   = (__half*)(uni + xbytes);
    size_t total_need = (size_t)(w - (char*)d_ws);
    const bool useBuckets = (ws_size >= total_need) && (nbk <= NBKMAX);

    const int B = 256;
    int nbN = (N + B - 1) / B;
    int nbE = (E + B - 1) / B;

    if (useBuckets) {
        k_zero<<<(nbk + B - 1) / B, B, 0, stream>>>(bcnt, nbk);
        int nbA = (E + CHUNK - 1) / CHUNK;
        k_binA<<<nbA, B, 0, stream>>>(src, dst, bcnt, ebDS, E, nbk);
        k_binB<<<nbk, B, 0, stream>>>(bcnt, ebDS, counts, N);
        k_block_sums<<<nbN, B, 0, stream>>>(counts, partial, N);
        k_scan_partials<<<1, 1024, 0, stream>>>(partial, nbN);
        k_scan_final<<<nbN, B, 0, stream>>>(counts, partial, off, dinv, N);
        k_binC<<<nbk, B, 0, stream>>>(bcnt, ebDS, off, col, N, E);
    } else {
        k_zero<<<nbN, B, 0, stream>>>(counts, N);
        k_zero<<<nbN, B, 0, stream>>>(cursor, N);
        k_hist<<<nbE, B, 0, stream>>>(dst, counts, E);
        k_block_sums<<<nbN, B, 0, stream>>>(counts, partial, N);
        k_scan_partials<<<1, 1024, 0, stream>>>(partial, nbN);
        k_scan_final<<<nbN, B, 0, stream>>>(counts, partial, off, dinv, N);
        k_scatter<<<nbE, B, 0, stream>>>(src, dst, off, cursor, col, E);
    }

    // fused weights + projection to fp16 padded rows (with dinv pre-scale)
    k_wc<<<1, 256, 0, stream>>>(Wsgc, bsgc, Whead, bhead, Wc, bc);
    k_proj<<<(N + 31) / 32, 256, 0, stream>>>(x, Wc, dinv, xA, N);

    // 3 hops in u-space: xA -> xB -> xA -> out(final: dinv scale + bias)
    int hopBlocks = (N * 64 + B - 1) / B;
    k_hop<<<hopBlocks, B, 0, stream>>>(xA, xB, out, off, counts, dinv, col, bc, 0, N);
    k_hop<<<hopBlocks, B, 0, stream>>>(xB, xA, out, off, counts, dinv, col, bc, 0, N);
    k_hop<<<hopBlocks, B, 0, stream>>>(xA, xB, out, off, counts, dinv, col, bc, 1, N);
}

// Round 6
// 248.791 us; speedup vs baseline: 2.6663x; 1.0161x over previous
//
#include <hip/hip_runtime.h>
#include <hip/hip_bf16.h>
#include <hip/hip_fp16.h>

#define DIMI 64
#define DIMO 40
#define DLO  32           // xL features (64B row = 1 line)
#define DHI  8            // xH features (16B row; 1.6MB array, L2-resident)

#define NBK_SHIFT 9
#define NPBK 512          // dst-nodes per bucket
#define NBKMAX 256
#define BCAP 9216         // bucket capacity (mean 8192, +11 sigma)
#define CHUNK 4096        // edges per binA block

// ---------------- CSR build: LDS-sorted counting-sort path ----------------

__global__ void k_zero(int* __restrict__ p, int n) {
    int i = blockIdx.x * blockDim.x + threadIdx.x;
    if (i < n) p[i] = 0;
}

// Phase A: bin CHUNK edges into 512-node buckets; LDS-sort; coalesced writeout.
__global__ void k_binA(const int* __restrict__ src, const int* __restrict__ dst,
                       int* __restrict__ bcnt, int2* __restrict__ ebDS,
                       int E, int nbk) {
    __shared__ int h[NBKMAX];   // hist -> inclusive scan
    __shared__ int lb[NBKMAX];  // local exclusive base
    __shared__ int lc[NBKMAX];  // local cursor
    __shared__ int gb[NBKMAX];  // global run base (within bucket)
    __shared__ int2 eb[CHUNK];  // LDS-sorted (d,s) records
    int t = threadIdx.x;
    int e0 = blockIdx.x * CHUNK;
    int e1 = min(e0 + CHUNK, E);
    int nE = e1 - e0;
    h[t] = 0;
    __syncthreads();
    int d[CHUNK / 256], s[CHUNK / 256];
    #pragma unroll
    for (int u = 0; u < CHUNK / 256; u++) {
        int idx = e0 + t + u * 256;
        if (idx < e1) {
            d[u] = dst[idx];
            s[u] = src[idx];
            atomicAdd(&h[d[u] >> NBK_SHIFT], 1);
        }
    }
    __syncthreads();
    int orig = h[t];
    for (int o = 1; o < 256; o <<= 1) {   // inclusive Hillis-Steele scan
        int v = (t >= o) ? h[t - o] : 0;
        __syncthreads();
        h[t] += v;
        __syncthreads();
    }
    lb[t] = h[t] - orig;
    lc[t] = 0;
    gb[t] = orig ? atomicAdd(&bcnt[t], orig) : 0;  // reserve dense global run
    __syncthreads();
    #pragma unroll
    for (int u = 0; u < CHUNK / 256; u++) {
        int idx = e0 + t + u * 256;
        if (idx < e1) {
            int b = d[u] >> NBK_SHIFT;
            int r = atomicAdd(&lc[b], 1);
            eb[lb[b] + r] = make_int2(d[u], s[u]);
        }
    }
    __syncthreads();
    for (int i = t; i < nE; i += 256) {
        int2 e = eb[i];
        int b = e.x >> NBK_SHIFT;
        int slot = gb[b] + (i - lb[b]);
        if (slot < BCAP) ebDS[(size_t)b * BCAP + slot] = e;
    }
}

// exclusive scan of min(bcnt,BCAP) over nbk (<=256) buckets -> bbase
__global__ void k_scan_bcnt(const int* __restrict__ bcnt, int* __restrict__ bbase, int nbk) {
    __shared__ int s[256];
    int t = threadIdx.x;
    int orig = (t < nbk) ? min(bcnt[t], BCAP) : 0;
    s[t] = orig;
    __syncthreads();
    for (int o = 1; o < 256; o <<= 1) {
        int v = (t >= o) ? s[t - o] : 0;
        __syncthreads();
        s[t] += v;
        __syncthreads();
    }
    if (t < nbk) bbase[t] = s[t] - orig;
}

// Fused phase B+C: per-bucket hist -> 512-wide LDS scan -> counts/off/dinv
// dense writes -> LDS place -> coalesced col writeout.
__global__ void k_binBC(const int* __restrict__ bcnt, const int* __restrict__ bbase,
                        const int2* __restrict__ ebDS,
                        int* __restrict__ counts, int* __restrict__ off,
                        float* __restrict__ dinv, int* __restrict__ col,
                        int N) {
    __shared__ int sh[NPBK];    // hist -> inclusive scan
    __shared__ int so[NPBK];    // orig -> local exclusive prefix
    __shared__ int slc[NPBK];   // cursor
    __shared__ int scol[BCAP];
    int b = blockIdx.x, t = threadIdx.x;
    sh[t] = 0; sh[t + 256] = 0;
    __syncthreads();
    int n = min(bcnt[b], BCAP);
    size_t base = (size_t)b * BCAP;
    for (int i = t; i < n; i += 256)
        atomicAdd(&sh[ebDS[base + i].x & (NPBK - 1)], 1);
    __syncthreads();
    so[t] = sh[t]; so[t + 256] = sh[t + 256];
    __syncthreads();
    for (int o = 1; o < NPBK; o <<= 1) {   // inclusive scan over 512
        int v0 = (t >= o) ? sh[t - o] : 0;
        int v1 = (t + 256 >= o) ? sh[t + 256 - o] : 0;
        __syncthreads();
        sh[t] += v0; sh[t + 256] += v1;
        __syncthreads();
    }
    int gbase = bbase[b];
    int d0 = b << NBK_SHIFT;
    #pragma unroll
    for (int half = 0; half < 2; half++) {
        int j = t + half * 256;
        int orig = so[j];
        int excl = sh[j] - orig;
        int dd = d0 + j;
        if (dd < N) {
            counts[dd] = orig;
            off[dd] = gbase + excl;
            dinv[dd] = rsqrtf((float)(orig + 1));
        }
        so[j] = excl;   // repurpose as local placement base
        slc[j] = 0;
    }
    __syncthreads();
    for (int i = t; i < n; i += 256) {
        int2 e = ebDS[base + i];
        int local = e.x & (NPBK - 1);
        int r = atomicAdd(&slc[local], 1);
        scol[so[local] + r] = e.y;
    }
    __syncthreads();
    for (int i = t; i < n; i += 256) col[gbase + i] = scol[i];
}

// ---------------- CSR build: fallback (random-write) path ----------------

__global__ void k_hist(const int* __restrict__ dst, int* __restrict__ counts, int E) {
    int i = blockIdx.x * blockDim.x + threadIdx.x;
    if (i < E) atomicAdd(&counts[dst[i]], 1);
}

__global__ void k_scatter(const int* __restrict__ src, const int* __restrict__ dst,
                          const int* __restrict__ off, int* __restrict__ cursor,
                          int* __restrict__ col, int E) {
    int i = blockIdx.x * blockDim.x + threadIdx.x;
    if (i < E) {
        int d = dst[i];
        int p = off[d] + atomicAdd(&cursor[d], 1);
        col[p] = src[i];
    }
}

__global__ void k_block_sums(const int* __restrict__ counts, int* __restrict__ partial, int n) {
    __shared__ int s[256];
    int i = blockIdx.x * 256 + threadIdx.x;
    s[threadIdx.x] = (i < n) ? counts[i] : 0;
    __syncthreads();
    for (int st = 128; st > 0; st >>= 1) {
        if (threadIdx.x < st) s[threadIdx.x] += s[threadIdx.x + st];
        __syncthreads();
    }
    if (threadIdx.x == 0) partial[blockIdx.x] = s[0];
}

__global__ void k_scan_partials(int* partial, int nb) {
    __shared__ int s[1024];
    int t = threadIdx.x;
    int orig = (t < nb) ? partial[t] : 0;
    s[t] = orig;
    __syncthreads();
    for (int o = 1; o < 1024; o <<= 1) {
        int v = (t >= o) ? s[t - o] : 0;
        __syncthreads();
        s[t] += v;
        __syncthreads();
    }
    if (t < nb) partial[t] = s[t] - orig;
}

__global__ void k_scan_final(const int* __restrict__ counts, const int* __restrict__ partial,
                             int* __restrict__ off, float* __restrict__ dinv, int n) {
    __shared__ int s[256];
    int t = threadIdx.x;
    int i = blockIdx.x * 256 + t;
    int orig = (i < n) ? counts[i] : 0;
    s[t] = orig;
    __syncthreads();
    for (int o = 1; o < 256; o <<= 1) {
        int v = (t >= o) ? s[t - o] : 0;
        __syncthreads();
        s[t] += v;
        __syncthreads();
    }
    if (i < n) {
        off[i] = s[t] - orig + partial[blockIdx.x];
        dinv[i] = rsqrtf((float)(orig + 1));
    }
}

// ---------------- dense math ----------------

__global__ void k_wc(const float* __restrict__ Wsgc, const float* __restrict__ bsgc,
                     const float* __restrict__ Whead, const float* __restrict__ bhead,
                     float* __restrict__ Wc, float* __restrict__ bc) {
    __shared__ float sA[DIMI * DIMI];
    __shared__ float sB[DIMI * DIMO];
    int t = threadIdx.x;
    for (int i = t; i < DIMI * DIMI; i += 256) sA[i] = Wsgc[i];
    for (int i = t; i < DIMI * DIMO; i += 256) sB[i] = Whead[i];
    __syncthreads();
    for (int o = t; o < DIMI * DIMO; o += 256) {
        int k = o / DIMO, j = o % DIMO;
        float acc = 0.f;
        #pragma unroll
        for (int m = 0; m < DIMI; m++) acc += sA[k * DIMI + m] * sB[m * DIMO + j];
        Wc[o] = acc;
    }
    if (t < DIMO) {
        float acc = bhead[t];
        #pragma unroll
        for (int m = 0; m < DIMI; m++) acc += bsgc[m] * sB[m * DIMO + t];
        bc[t] = acc;
    }
}

// u0 = dinv * (x @ Wc), written split: xL[N][32] fp16, xH[N][8] fp16
__global__ void k_proj(const float* __restrict__ x, const float* __restrict__ Wc,
                       const float* __restrict__ dinv,
                       __half* __restrict__ yL, __half* __restrict__ yH, int N) {
    __shared__ float sX[32 * DIMI];
    __shared__ float sW[DIMI * DIMO];
    int t = threadIdx.x;
    int n0 = blockIdx.x * 32;
    for (int i = t; i < DIMI * DIMO; i += 256) sW[i] = Wc[i];
    const float4* x4 = (const float4*)x;
    float4* sX4 = (float4*)sX;
    for (int i = t; i < 32 * (DIMI / 4); i += 256) {
        int r = n0 + i / (DIMI / 4);
        sX4[i] = (r < N) ? x4[(long)r * (DIMI / 4) + (i & (DIMI / 4 - 1))]
                         : make_float4(0.f, 0.f, 0.f, 0.f);
    }
    __syncthreads();
    for (int o = t; o < 32 * DIMO; o += 256) {
        int li = o / DIMO, j = o % DIMO;
        int node = n0 + li;
        if (node < N) {
            float acc = 0.f;
            #pragma unroll
            for (int k = 0; k < DIMI; k++) acc += sX[li * DIMI + k] * sW[k * DIMO + j];
            __half v = __float2half(dinv[node] * acc);
            if (j < DLO) yL[(long)node * DLO + j] = v;
            else         yH[(long)node * DHI + (j - DLO)] = v;
        }
    }
}

// one wave per node; lanes 0-31 read xL (64B line), lanes 32-39 read xH
// (16B row in L2-resident 1.6MB array), lanes 40-63 duplicate lane 39.
// u-space hop: out = scale * ( sum_{nbr} in[nbr] + in[self] )
__global__ void k_hop(const __half* __restrict__ xLin, const __half* __restrict__ xHin,
                      __half* __restrict__ xLout, __half* __restrict__ xHout,
                      float* __restrict__ outF,
                      const int* __restrict__ off, const int* __restrict__ counts,
                      const float* __restrict__ dinv,
                      const int* __restrict__ col,
                      const float* __restrict__ bc, int finalHop, int N) {
    int gtid = blockIdx.x * blockDim.x + threadIdx.x;
    int node = gtid >> 6;
    int lane = threadIdx.x & 63;
    if (node >= N) return;
    int l = lane < DIMO ? lane : DIMO - 1;
    const __half* base; long stride; int foff;
    if (l < DLO) { base = xLin; stride = DLO; foff = l; }
    else         { base = xHin; stride = DHI; foff = l - DLO; }
    int rs = off[node];
    int cnt = counts[node];
    int cidx = (lane < cnt) ? col[rs + lane] : node;  // coalesced preload
    float acc = __half2float(base[(long)node * stride + foff]);  // self loop
    int cmain = cnt < 64 ? cnt : 64;
    int e = 0;
    for (; e + 16 <= cmain; e += 16) {
        float v[16];
        #pragma unroll
        for (int u = 0; u < 16; u++) {
            int c = __shfl(cidx, e + u, 64);
            v[u] = __half2float(base[(long)c * stride + foff]);
        }
        float s01 = (v[0] + v[1]) + (v[2] + v[3]);
        float s23 = (v[4] + v[5]) + (v[6] + v[7]);
        float s45 = (v[8] + v[9]) + (v[10] + v[11]);
        float s67 = (v[12] + v[13]) + (v[14] + v[15]);
        acc += (s01 + s23) + (s45 + s67);
    }
    for (; e + 4 <= cmain; e += 4) {
        float v[4];
        #pragma unroll
        for (int u = 0; u < 4; u++) {
            int c = __shfl(cidx, e + u, 64);
            v[u] = __half2float(base[(long)c * stride + foff]);
        }
        acc += (v[0] + v[1]) + (v[2] + v[3]);
    }
    for (; e < cmain; e++) {
        int c = __shfl(cidx, e, 64);
        acc += __half2float(base[(long)c * stride + foff]);
    }
    for (int e2 = 64; e2 < cnt; e2++) {  // deg>64: vanishingly rare
        int c = col[rs + e2];
        acc += __half2float(base[(long)c * stride + foff]);
    }
    float di = dinv[node];
    float scale = finalHop ? di : di * di;
    if (lane < DIMO) {
        float r = scale * acc;
        if (finalHop) {
            outF[(long)node * DIMO + lane] = r + bc[lane];
        } else {
            __half h = __float2half(r);
            if (lane < DLO) xLout[(long)node * DLO + lane] = h;
            else            xHout[(long)node * DHI + (lane - DLO)] = h;
        }
    }
}

// ---------------- launch ----------------

extern "C" void kernel_launch(void* const* d_in, const int* in_sizes, int n_in,
                              void* d_out, int out_size, void* d_ws, size_t ws_size,
                              hipStream_t stream) {
    const float* x     = (const float*)d_in[0];
    const int*   ei    = (const int*)d_in[1];
    const float* Wsgc  = (const float*)d_in[2];
    const float* bsgc  = (const float*)d_in[3];
    const float* Whead = (const float*)d_in[4];
    const float* bhead = (const float*)d_in[5];
    float* out = (float*)d_out;

    const int N = in_sizes[0] / DIMI;
    const int E = in_sizes[1] / 2;
    const int* src = ei;
    const int* dst = ei + E;
    const int nbk = (N + NPBK - 1) >> NBK_SHIFT;

    // carve workspace (256B-aligned)
    char* w = (char*)d_ws;
    auto carve = [&](size_t bytes) {
        char* p = w;
        w += (bytes + 255) & ~(size_t)255;
        return p;
    };
    int*   counts  = (int*)  carve((size_t)N * 4);
    int*   cursor  = (int*)  carve((size_t)N * 4);
    int*   off     = (int*)  carve((size_t)N * 4);
    float* dinv    = (float*)carve((size_t)N * 4);
    int*   partial = (int*)  carve(1024 * 4);
    int*   col     = (int*)  carve((size_t)E * 4);
    float* Wc      = (float*)carve(DIMI * DIMO * 4);
    float* bc      = (float*)carve(DIMO * 4);
    int*   bcnt    = (int*)  carve((size_t)nbk * 4);
    int*   bbase   = (int*)  carve((size_t)nbk * 4);
    // union: ebDS (CSR staging, dead before k_proj) aliases xL/xH double buffers
    size_t lbytes  = (size_t)N * DLO * 2;
    size_t hbytes  = (size_t)N * DHI * 2;
    size_t xbytes  = lbytes + hbytes;
    size_t ebytes  = (size_t)nbk * BCAP * 8;
    size_t ubytes  = ebytes > 2 * xbytes ? ebytes : 2 * xbytes;
    char*  uni     = carve(ubytes);
    int2*   ebDS = (int2*)uni;
    __half* xLA  = (__half*)uni;
    __half* xHA  = (__half*)(uni + lbytes);
    __half* xLB  = (__half*)(uni + xbytes);
    __half* xHB  = (__half*)(uni + xbytes + lbytes);
    size_t total_need = (size_t)(w - (char*)d_ws);
    const bool useBuckets = (ws_size >= total_need) && (nbk <= NBKMAX);

    const int B = 256;
    int nbN = (N + B - 1) / B;
    int nbE = (E + B - 1) / B;

    if (useBuckets) {
        k_zero<<<(nbk + B - 1) / B, B, 0, stream>>>(bcnt, nbk);
        int nbA = (E + CHUNK - 1) / CHUNK;
        k_binA<<<nbA, B, 0, stream>>>(src, dst, bcnt, ebDS, E, nbk);
        k_scan_bcnt<<<1, 256, 0, stream>>>(bcnt, bbase, nbk);
        k_binBC<<<nbk, B, 0, stream>>>(bcnt, bbase, ebDS, counts, off, dinv, col, N);
    } else {
        k_zero<<<nbN, B, 0, stream>>>(counts, N);
        k_zero<<<nbN, B, 0, stream>>>(cursor, N);
        k_hist<<<nbE, B, 0, stream>>>(dst, counts, E);
        k_block_sums<<<nbN, B, 0, stream>>>(counts, partial, N);
        k_scan_partials<<<1, 1024, 0, stream>>>(partial, nbN);
        k_scan_final<<<nbN, B, 0, stream>>>(counts, partial, off, dinv, N);
        k_scatter<<<nbE, B, 0, stream>>>(src, dst, off, cursor, col, E);
    }

    // fused weights + projection to split fp16 arrays (with dinv pre-scale)
    k_wc<<<1, 256, 0, stream>>>(Wsgc, bsgc, Whead, bhead, Wc, bc);
    k_proj<<<(N + 31) / 32, 256, 0, stream>>>(x, Wc, dinv, xLA, xHA, N);

    // 3 hops in u-space: A -> B -> A -> out(final: dinv scale + bias)
    int hopBlocks = (N * 64 + B - 1) / B;
    k_hop<<<hopBlocks, B, 0, stream>>>(xLA, xHA, xLB, xHB, out, off, counts, dinv, col, bc, 0, N);
    k_hop<<<hopBlocks, B, 0, stream>>>(xLB, xHB, xLA, xHA, out, off, counts, dinv, col, bc, 0, N);
    k_hop<<<hopBlocks, B, 0, stream>>>(xLA, xHA, xLB, xHB, out, off, counts, dinv, col, bc, 1, N);
}